// Round 8
// baseline (234.799 us; speedup 1.0000x reference)
//
#include <hip/hip_runtime.h>
#include <math.h>

// MMD loss, fp16 MFMA. N=M=4096, D=1024, sigma^2=2025.
// Round 18: FAT WAVE TILES on the R7 base. R7 (packing + true-0-conflict
// swizzle) measured 84.8us / MfmaUtil 35% -- near the 64x64-wave shape's
// structural ceiling (~40%): per-SIMD MFMA work is fixed at ~81k cy of a
// 203k cy wall, with LDS 48%, L2 36%, HBM 24% (nothing saturated). Raise
// the ceiling, not the schedule: per-wave 128x64 (block 256x128, 4 waves
// 2x2), 32 MFMA per 12KB frag reads (384 B/MFMA vs 512) + 187 B/MFMA
// staging; barriers/drains/decode per FLOP halved. acc 8x4 floatx4 = 128
// VGPR -> ~2 waves/SIMD, 2 blocks/CU (LDS 24.1KB). Norms now loaded in the
// epilogue (after frag regs die) to protect the register budget.
// Unchanged from R7: packed K-major panels (1KB-contiguous glds), split
// ldsA/ldsB with f(r)=((r>>1)&3) chunk swizzle (measured 0 conflicts;
// per-quad bank pattern identical for 8 A-frags), 2-barrier drain loop,
// fp64 partials, 3 launches. Grid: R1's verified triangular 256x128 cover
// (1056 blocks; straddle tiles w=1, j>=2i+2 tiles w=2, diagonal analytic).

typedef _Float16 f16_t;
typedef _Float16 f16x4 __attribute__((ext_vector_type(4)));
typedef _Float16 f16x8 __attribute__((ext_vector_type(8)));
typedef float floatx4 __attribute__((ext_vector_type(4)));

#define NROWS 4096
#define MROWS 4096
#define DDIM  1024
#define BM    256                   // A rows per block
#define BN    128                   // B rows per block
#define BK    32                    // fp16 elements per K-step (64 B/row)
#define NKT   (DDIM / BK)           // 32 K-steps
#define PSTRIDE (4096 * BK)         // f16 elems per packed K-panel (256 KB)
#define NTR   (NROWS / BM)          // 16 row tiles
#define NTC   (NROWS / BN)          // 32 col tiles
#define XXB   272                   // sum_{i=0..15} (32-2i) triangular tiles
#define NBLK  (2 * XXB + NTR * NTC) // 1056 blocks

// ---------------------------------------------------------------- convert
// Wave-per-row: 2048 blocks x 4 waves cover 8192 rows. Each lane loads
// 4 float4 (fully coalesced), converts to fp16, stores to the PACKED layout
// Xp[kt][row][32]: lane l, iter c covers k = c*256+l*4 -> panel c*8+(l>>3),
// pos (l&7)*4. Norm of the ROUNDED row shuffle-reduced in-wave.
__global__ __launch_bounds__(256) void convert_kernel(
    const float* __restrict__ X, const float* __restrict__ Y,
    f16_t* __restrict__ Xp, f16_t* __restrict__ Yp,
    float* __restrict__ nx, float* __restrict__ ny) {
    const int wid  = threadIdx.x >> 6;
    const int lane = threadIdx.x & 63;
    const int row  = blockIdx.x * 4 + wid;        // 0..8191
    const float* src;
    f16_t* dstp;
    float* nrm;
    int r;
    if (row < NROWS) {
        r = row;         src = X + (size_t)r * DDIM;
        dstp = Xp;  nrm = nx;
    } else {
        r = row - NROWS; src = Y + (size_t)r * DDIM;
        dstp = Yp;  nrm = ny;
    }
    const float4* s4 = (const float4*)src;        // 256 float4 per row
    float s = 0.f;
    #pragma unroll
    for (int c = 0; c < 4; c++) {
        float4 v = s4[c * 64 + lane];
        f16x4 h;
        h[0] = (f16_t)v.x; h[1] = (f16_t)v.y;
        h[2] = (f16_t)v.z; h[3] = (f16_t)v.w;
        // k = c*256 + lane*4 -> kt = c*8 + (lane>>3), pos = (lane&7)*4
        *(f16x4*)(dstp + (size_t)(c * 8 + (lane >> 3)) * PSTRIDE
                       + (size_t)r * BK + (lane & 7) * 4) = h;
        float h0 = (float)h[0], h1 = (float)h[1];
        float h2 = (float)h[2], h3 = (float)h[3];
        s += h0 * h0 + h1 * h1 + h2 * h2 + h3 * h3;
    }
    #pragma unroll
    for (int off = 32; off > 0; off >>= 1) s += __shfl_down(s, off);
    if (lane == 0) nrm[r] = s;
}

// ---------------------------------------------------------------- main GEMM
__global__ __launch_bounds__(256) void mmd_mfma(
    const f16_t* __restrict__ Xp, const f16_t* __restrict__ Yp,
    const float* __restrict__ nx, const float* __restrict__ ny,
    double* __restrict__ partials) {
    // Split A/B tiles: A 256x32 (16KB), B 128x32 (8KB). Row r stores
    // logical chunk c (16B) at phys chunk c ^ ((r>>1)&3) -- measured 0
    // bank conflicts (R7).
    __shared__ __align__(16) f16_t ldsA[BM * BK];
    __shared__ __align__(16) f16_t ldsB[BN * BK];
    __shared__ double wred[4];

    const int b = blockIdx.x;
    const f16_t *Ap, *Bp;             // packed panel bases (panel 0)
    const float *nAp, *nBp;
    int arow0, brow0;                 // global row offsets of the tiles
    double coef;
    if (b < 2 * XXB) {
        int u = (b < XXB) ? b : b - XXB;
        int i = 0;
        while (u >= NTC - 2 * i) { u -= NTC - 2 * i; i++; }
        const int ti = i, tj = 2 * i + u;         // tj in [2i, 32)
        const double w = (tj >= 2 * i + 2) ? 2.0 : 1.0;  // straddle tiles w=1
        const f16_t* base;
        const float* nb_;
        double denom;
        if (b < XXB) { base = Xp; nb_ = nx; denom = (double)NROWS * (double)(NROWS - 1); }
        else         { base = Yp; nb_ = ny; denom = (double)MROWS * (double)(MROWS - 1); }
        Ap = base; Bp = base;
        arow0 = ti * BM;  brow0 = tj * BN;
        nAp = nb_ + arow0;  nBp = nb_ + brow0;
        coef = w / denom;
    } else {
        const int u = b - 2 * XXB;
        const int ti = u >> 5, tj = u & 31;
        Ap = Xp; Bp = Yp;
        arow0 = ti * BM;  brow0 = tj * BN;
        nAp = nx + arow0;  nBp = ny + brow0;
        coef = -2.0 / ((double)NROWS * (double)MROWS);
    }

    const int t    = threadIdx.x;
    const int wave = t >> 6;            // 0..3; waves 2x2
    const int lane = t & 63;
    const int wm   = wave >> 1;         // 0..1 : 128 A-rows each
    const int wn   = wave & 1;          // 0..1 : 64 B-rows each

    // staging: 24 glds instrs (A 16 row-groups + B 8 row-groups of 16 rows);
    // wave w issues instrs w*6 .. w*6+5. Per instr: 16 rows x 64B =
    // CONTIGUOUS 1KB in the packed panel. glds writes linearly: lane l ->
    // row lr=l>>2, phys chunk l&3; lane fetches global chunk
    // (l&3)^((l>>3)&3) so phys chunk p of row r holds logical p^((r>>1)&3).
    const int lr = lane >> 2;           // 0..15 within row-group
    const int lc = (lane & 3) ^ ((lane >> 3) & 3);
    const f16_t* gsrc[6];
    f16_t* ldst[6];
    #pragma unroll
    for (int i = 0; i < 6; i++) {
        int idx = wave * 6 + i;         // 0..23
        if (idx < 16) {                 // A row-group
            gsrc[i] = Ap + (size_t)(arow0 + idx * 16 + lr) * BK + lc * 8;
            ldst[i] = ldsA + idx * 16 * BK;
        } else {                        // B row-group
            int rg = idx - 16;
            gsrc[i] = Bp + (size_t)(brow0 + rg * 16 + lr) * BK + lc * 8;
            ldst[i] = ldsB + rg * 16 * BK;
        }
    }

    const int m    = lane & 15;         // row within 16x16 subtile
    const int quad = lane >> 4;         // k-chunk: k = quad*8 + j
    // read-side swizzled chunk offset: phys = quad ^ ((row>>1)&3); rows are
    // s*16 + m so f depends only on m.
    const int sw8  = (quad ^ ((m >> 1) & 3)) * 8;

    floatx4 acc[8][4];
    #pragma unroll
    for (int i = 0; i < 8; i++)
        #pragma unroll
        for (int j = 0; j < 4; j++) acc[i][j] = (floatx4){0.f, 0.f, 0.f, 0.f};

    for (int kt = 0; kt < NKT; kt++) {
        const size_t ko = (size_t)kt * PSTRIDE;   // next packed K-panel
        __syncthreads();                 // previous compute done before overwrite
        #pragma unroll
        for (int i = 0; i < 6; i++) {
            __builtin_amdgcn_global_load_lds(
                (const __attribute__((address_space(1))) void*)(gsrc[i] + ko),
                (__attribute__((address_space(3))) void*)ldst[i],
                16, 0, 0);
        }
        __syncthreads();                 // drains vmcnt before barrier

        f16x8 ah[8], bh[4];
        #pragma unroll
        for (int s = 0; s < 8; s++)
            ah[s] = *(const f16x8*)&ldsA[(wm * 128 + s * 16 + m) * BK + sw8];
        #pragma unroll
        for (int s = 0; s < 4; s++)
            bh[s] = *(const f16x8*)&ldsB[(wn * 64 + s * 16 + m) * BK + sw8];
        #pragma unroll
        for (int i = 0; i < 8; i++)
            #pragma unroll
            for (int j = 0; j < 4; j++)
                acc[i][j] = __builtin_amdgcn_mfma_f32_16x16x32_f16(ah[i], bh[j], acc[i][j], 0, 0, 0);
    }

    // epilogue: C/D layout col=lane&15 (B-row), row=quad*4+reg (A-row).
    // Norms loaded HERE (frag registers are dead; one-time latency, ~1% of
    // block wall) to keep loop-time VGPR <= 256.
    const float inv_s2 = 1.0f / 2025.0f;
    float nbv[4];
    #pragma unroll
    for (int j = 0; j < 4; j++) nbv[j] = nBp[wn * 64 + j * 16 + m];
    float lsum = 0.f;
    #pragma unroll
    for (int i = 0; i < 8; i++) {
        float4 na4 = *(const float4*)&nAp[wm * 128 + i * 16 + quad * 4];
        #pragma unroll
        for (int j = 0; j < 4; j++)
            #pragma unroll
            for (int r = 0; r < 4; r++) {
                float arg = (2.f * acc[i][j][r]
                             - (&na4.x)[r] - nbv[j]) * inv_s2;
                lsum += __expf(arg);
            }
    }

    // in-wave fp64 reduce (no barriers), then 4-wave LDS combine; plain store
    double d = (double)lsum;
    #pragma unroll
    for (int off = 32; off > 0; off >>= 1) d += __shfl_down(d, off);
    if (lane == 0) wred[wave] = d;
    __syncthreads();
    if (t == 0)
        partials[b] = (wred[0] + wred[1] + wred[2] + wred[3]) * coef;
}

__global__ __launch_bounds__(256) void final_reduce(const double* __restrict__ partials,
                                                    float* __restrict__ out) {
    __shared__ double red[256];
    int t = threadIdx.x;
    double s = 0.0;
    for (int i = t; i < NBLK; i += 256) s += partials[i];
    red[t] = s;
    __syncthreads();
    for (int off = 128; off > 0; off >>= 1) {
        if (t < off) red[t] += red[t + off];
        __syncthreads();
    }
    if (t == 0) {
        // analytic diagonal subtraction: 1/(n-1) + 1/(m-1)
        double mmd = red[0] - 1.0 / (double)(NROWS - 1) - 1.0 / (double)(MROWS - 1);
        out[0] = (float)mmd;
    }
}

extern "C" void kernel_launch(void* const* d_in, const int* in_sizes, int n_in,
                              void* d_out, int out_size, void* d_ws, size_t ws_size,
                              hipStream_t stream) {
    const float* X = (const float*)d_in[0];   // inputs  [4096,1024] fp32
    const float* Y = (const float*)d_in[1];   // samples [4096,1024] fp32
    float* out = (float*)d_out;

    // workspace: partials | nx | ny | Xp | Yp  (~16.7 MB)
    char* p = (char*)d_ws;
    double* partials = (double*)p;            p += ((size_t)NBLK * sizeof(double) + 255) & ~255ULL;
    float* nx = (float*)p;                    p += (size_t)NROWS * sizeof(float);
    float* ny = (float*)p;                    p += (size_t)MROWS * sizeof(float);
    f16_t* Xp = (f16_t*)p;                    p += (size_t)NROWS * DDIM * sizeof(f16_t);
    f16_t* Yp = (f16_t*)p;

    convert_kernel<<<(NROWS + MROWS) / 4, 256, 0, stream>>>(X, Y, Xp, Yp, nx, ny);
    mmd_mfma<<<NBLK, 256, 0, stream>>>(Xp, Yp, nx, ny, partials);
    final_reduce<<<1, 256, 0, stream>>>(partials, out);
}

// Round 9
// 164.741 us; speedup vs baseline: 1.4253x; 1.4253x over previous
//
#include <hip/hip_runtime.h>
#include <math.h>

// MMD loss, fp16 MFMA. N=M=4096, D=1024, sigma^2=2025.
// Round 19: BK=64 SUB-PHASED on the R7 base. R8 post-mortem: trace VGPR
// excludes acc AGPRs (unified file): 168+128=296/wave -> 1 wave/SIMD ->
// 2x slower. LAW: keep arch+acc <= ~150 (3 waves/SIMD). R7 (84.8us,
// MfmaUtil 35%, conflicts 0) budget: MFMA 35% + LDS ~48% + ~260 drain
// barrier pairs/CU. This round halves the barrier pairs WITHOUT touching
// registers: BK=64 per K-step (16 steps), ONE syncthreads-pair per step,
// fragments still read 32-deep into the SAME 8 f16x8 regs (khalf0 reads ->
// 16 MFMA -> khalf1 reads -> 16 MFMA; lgkmcnt orders, no barrier between).
// Panels repacked [kt][row][64] (rows 128B); staging instrs stay 1KB
// contiguous (8 rows x 128B). Swizzle re-derived for 128B rows: 16B-granule
// XOR phys = g ^ (r&7); every quarter-wave covers 32 banks exactly 2-way
// (free) on BOTH linear glds writes and swizzled ds_read_b128 -- same proof
// shape as R7's measured-0 pattern. Everything else R7 verbatim: 128x128
// block, 4 waves 2x2, triangular 2080-block grid, fp64 partials, 3 launches,
// norms loaded in epilogue.

typedef _Float16 f16_t;
typedef _Float16 f16x4 __attribute__((ext_vector_type(4)));
typedef _Float16 f16x8 __attribute__((ext_vector_type(8)));
typedef float floatx4 __attribute__((ext_vector_type(4)));

#define NROWS 4096
#define MROWS 4096
#define DDIM  1024
#define BM    128
#define BKP   64                      // fp16 elements per K-step (128 B/row)
#define TILE  (BM * BKP)              // 8192 f16 per tile (16 KB)
#define NKT   (DDIM / BKP)            // 16 K-steps
#define PSTRIDE (4096 * BKP)          // f16 elems per packed K-panel (512 KB)
#define NT    (NROWS / BM)            // 32 tiles per dim
#define TRI   (NT * (NT + 1) / 2)     // 528 triangular tiles
#define NBLK  (2 * TRI + NT * NT)     // 2080 blocks

// ---------------------------------------------------------------- convert
// Wave-per-row: 2048 blocks x 4 waves cover 8192 rows. Each lane loads
// 4 float4 (fully coalesced), converts to fp16, stores to the PACKED layout
// Xp[kt][row][64]: lane l, iter c covers k = c*256+l*4 -> panel c*4+(l>>4),
// pos (l&15)*4 (16 lanes x 8B = 128B contiguous per panel). Norm of the
// ROUNDED row shuffle-reduced in-wave.
__global__ __launch_bounds__(256) void convert_kernel(
    const float* __restrict__ X, const float* __restrict__ Y,
    f16_t* __restrict__ Xp, f16_t* __restrict__ Yp,
    float* __restrict__ nx, float* __restrict__ ny) {
    const int wid  = threadIdx.x >> 6;
    const int lane = threadIdx.x & 63;
    const int row  = blockIdx.x * 4 + wid;        // 0..8191
    const float* src;
    f16_t* dstp;
    float* nrm;
    int r;
    if (row < NROWS) {
        r = row;         src = X + (size_t)r * DDIM;
        dstp = Xp;  nrm = nx;
    } else {
        r = row - NROWS; src = Y + (size_t)r * DDIM;
        dstp = Yp;  nrm = ny;
    }
    const float4* s4 = (const float4*)src;        // 256 float4 per row
    float s = 0.f;
    #pragma unroll
    for (int c = 0; c < 4; c++) {
        float4 v = s4[c * 64 + lane];
        f16x4 h;
        h[0] = (f16_t)v.x; h[1] = (f16_t)v.y;
        h[2] = (f16_t)v.z; h[3] = (f16_t)v.w;
        // k = c*256 + lane*4 -> kt = c*4 + (lane>>4), pos = (lane&15)*4
        *(f16x4*)(dstp + (size_t)(c * 4 + (lane >> 4)) * PSTRIDE
                       + (size_t)r * BKP + (lane & 15) * 4) = h;
        float h0 = (float)h[0], h1 = (float)h[1];
        float h2 = (float)h[2], h3 = (float)h[3];
        s += h0 * h0 + h1 * h1 + h2 * h2 + h3 * h3;
    }
    #pragma unroll
    for (int off = 32; off > 0; off >>= 1) s += __shfl_down(s, off);
    if (lane == 0) nrm[r] = s;
}

// ---------------------------------------------------------------- main GEMM
__global__ __launch_bounds__(256) void mmd_mfma(
    const f16_t* __restrict__ Xp, const f16_t* __restrict__ Yp,
    const float* __restrict__ nx, const float* __restrict__ ny,
    double* __restrict__ partials) {
    // Split A/B tiles: each 128x64 fp16 = 16 KB (32.8 KB total LDS).
    // Row r stores logical 16B-granule g at phys granule g ^ (r&7).
    __shared__ __align__(16) f16_t ldsA[TILE];
    __shared__ __align__(16) f16_t ldsB[TILE];
    __shared__ double wred[4];

    const int b = blockIdx.x;
    const f16_t *Ap, *Bp;             // packed panel bases (panel 0)
    const float *nA, *nB;
    int tr, tc;
    double coef;
    if (b < 2 * TRI) {
        int u = (b < TRI) ? b : b - TRI;
        int r = 0;
        while (u >= NT - r) { u -= NT - r; r++; }
        tr = r; tc = r + u;
        double w = (tr == tc) ? 1.0 : 2.0;   // off-diagonal tiles count twice
        if (b < TRI) { Ap = Xp; Bp = Xp; nA = nx; nB = nx;
                       coef = w / ((double)NROWS * (double)(NROWS - 1)); }
        else         { Ap = Yp; Bp = Yp; nA = ny; nB = ny;
                       coef = w / ((double)MROWS * (double)(MROWS - 1)); }
    } else {
        int u = b - 2 * TRI;
        tr = u >> 5; tc = u & 31;
        Ap = Xp; Bp = Yp; nA = nx; nB = ny;
        coef = -2.0 / ((double)NROWS * (double)MROWS);
    }

    const int t    = threadIdx.x;
    const int wave = t >> 6;            // 0..3; waves 2x2: wm=wave>>1, wn=wave&1
    const int lane = t & 63;
    const int wm   = wave >> 1;
    const int wn   = wave & 1;

    // staging: 32 glds instrs (2 tiles x 16 row-groups of 8 rows); wave w
    // issues instrs w*8 .. w*8+7. Per instr: 8 rows x 128B = CONTIGUOUS 1KB
    // in the packed panel. glds writes linearly: lane l -> row lr=l>>3,
    // phys granule l&7; lane fetches global granule (l&7)^(lr&7) so phys
    // granule p of row r holds logical p^(r&7).
    const int lr = lane >> 3;           // 0..7 within row-group
    const int lg = (lane & 7) ^ (lr & 7);
    const f16_t* gsrc[8];
    f16_t* ldst[8];
    #pragma unroll
    for (int i = 0; i < 8; i++) {
        int idx = wave * 8 + i;         // 0..31
        int tile = idx >> 4;            // 0=A, 1=B
        int rg   = idx & 15;            // row-group
        const f16_t* base = tile ? (Bp + (size_t)tc * BM * BKP)
                                 : (Ap + (size_t)tr * BM * BKP);
        gsrc[i] = base + (size_t)(rg * 8 + lr) * BKP + lg * 8;
        ldst[i] = (tile ? ldsB : ldsA) + rg * 8 * BKP;   // wave-uniform base
    }

    const int m    = lane & 15;         // row within 16x16 subtile
    const int quad = lane >> 4;         // k-chunk within khalf: k = quad*8+j
    // read-side swizzled granule offsets (f16 units): khalf h granule
    // (h*4+quad) ^ (m&7); rows are s*16+m so r&7 = m&7.
    const int g0 = ((quad)     ^ (m & 7)) * 8;
    const int g1 = ((4 + quad) ^ (m & 7)) * 8;

    floatx4 acc[4][4];
    #pragma unroll
    for (int i = 0; i < 4; i++)
        #pragma unroll
        for (int j = 0; j < 4; j++) acc[i][j] = (floatx4){0.f, 0.f, 0.f, 0.f};

    for (int kt = 0; kt < NKT; kt++) {
        const size_t ko = (size_t)kt * PSTRIDE;   // next packed K-panel
        __syncthreads();                 // previous compute done before overwrite
        #pragma unroll
        for (int i = 0; i < 8; i++) {
            __builtin_amdgcn_global_load_lds(
                (const __attribute__((address_space(1))) void*)(gsrc[i] + ko),
                (__attribute__((address_space(3))) void*)ldst[i],
                16, 0, 0);
        }
        __syncthreads();                 // drains vmcnt before barrier

        f16x8 ah[4], bh[4];
        // sub-phase 0: k = 0..31 of this step
        #pragma unroll
        for (int s = 0; s < 4; s++) {
            ah[s] = *(const f16x8*)&ldsA[(wm * 64 + s * 16 + m) * BKP + g0];
            bh[s] = *(const f16x8*)&ldsB[(wn * 64 + s * 16 + m) * BKP + g0];
        }
        #pragma unroll
        for (int i = 0; i < 4; i++)
            #pragma unroll
            for (int j = 0; j < 4; j++)
                acc[i][j] = __builtin_amdgcn_mfma_f32_16x16x32_f16(ah[i], bh[j], acc[i][j], 0, 0, 0);
        // sub-phase 1: k = 32..63 (same buffer, same regs; lgkmcnt orders)
        #pragma unroll
        for (int s = 0; s < 4; s++) {
            ah[s] = *(const f16x8*)&ldsA[(wm * 64 + s * 16 + m) * BKP + g1];
            bh[s] = *(const f16x8*)&ldsB[(wn * 64 + s * 16 + m) * BKP + g1];
        }
        #pragma unroll
        for (int i = 0; i < 4; i++)
            #pragma unroll
            for (int j = 0; j < 4; j++)
                acc[i][j] = __builtin_amdgcn_mfma_f32_16x16x32_f16(ah[i], bh[j], acc[i][j], 0, 0, 0);
    }

    // epilogue: C/D layout col=lane&15 (B-row), row=quad*4+reg (A-row).
    // Norms loaded here (frag regs dead) to keep loop-time registers low.
    const float inv_s2 = 1.0f / 2025.0f;
    float nbv[4];
    #pragma unroll
    for (int j = 0; j < 4; j++) nbv[j] = nB[tc * BM + wn * 64 + j * 16 + m];
    float lsum = 0.f;
    #pragma unroll
    for (int i = 0; i < 4; i++) {
        float4 na4 = *(const float4*)&nA[tr * BM + wm * 64 + i * 16 + quad * 4];
        #pragma unroll
        for (int j = 0; j < 4; j++)
            #pragma unroll
            for (int r = 0; r < 4; r++) {
                float arg = (2.f * acc[i][j][r] - (&na4.x)[r] - nbv[j]) * inv_s2;
                lsum += __expf(arg);
            }
    }

    // in-wave fp64 reduce (no barriers), then 4-wave LDS combine; plain store
    double d = (double)lsum;
    #pragma unroll
    for (int off = 32; off > 0; off >>= 1) d += __shfl_down(d, off);
    if (lane == 0) wred[wave] = d;
    __syncthreads();
    if (t == 0)
        partials[b] = (wred[0] + wred[1] + wred[2] + wred[3]) * coef;
}

__global__ __launch_bounds__(256) void final_reduce(const double* __restrict__ partials,
                                                    float* __restrict__ out) {
    __shared__ double red[256];
    int t = threadIdx.x;
    double s = 0.0;
    for (int i = t; i < NBLK; i += 256) s += partials[i];
    red[t] = s;
    __syncthreads();
    for (int off = 128; off > 0; off >>= 1) {
        if (t < off) red[t] += red[t + off];
        __syncthreads();
    }
    if (t == 0) {
        // analytic diagonal subtraction: 1/(n-1) + 1/(m-1)
        double mmd = red[0] - 1.0 / (double)(NROWS - 1) - 1.0 / (double)(MROWS - 1);
        out[0] = (float)mmd;
    }
}

extern "C" void kernel_launch(void* const* d_in, const int* in_sizes, int n_in,
                              void* d_out, int out_size, void* d_ws, size_t ws_size,
                              hipStream_t stream) {
    const float* X = (const float*)d_in[0];   // inputs  [4096,1024] fp32
    const float* Y = (const float*)d_in[1];   // samples [4096,1024] fp32
    float* out = (float*)d_out;

    // workspace: partials | nx | ny | Xp | Yp  (~16.7 MB)
    char* p = (char*)d_ws;
    double* partials = (double*)p;            p += ((size_t)NBLK * sizeof(double) + 255) & ~255ULL;
    float* nx = (float*)p;                    p += (size_t)NROWS * sizeof(float);
    float* ny = (float*)p;                    p += (size_t)MROWS * sizeof(float);
    f16_t* Xp = (f16_t*)p;                    p += (size_t)NROWS * DDIM * sizeof(f16_t);
    f16_t* Yp = (f16_t*)p;

    convert_kernel<<<(NROWS + MROWS) / 4, 256, 0, stream>>>(X, Y, Xp, Yp, nx, ny);
    mmd_mfma<<<NBLK, 256, 0, stream>>>(Xp, Yp, nx, ny, partials);
    final_reduce<<<1, 256, 0, stream>>>(partials, out);
}